// Round 8
// baseline (607.690 us; speedup 1.0000x reference)
//
#include <hip/hip_runtime.h>
#include <hip/hip_bf16.h>

#define HIDDEN 128

typedef __attribute__((ext_vector_type(8))) short s16x8;
typedef __attribute__((ext_vector_type(4))) short s16x4;
typedef __attribute__((ext_vector_type(4))) float f32x4;
typedef __attribute__((ext_vector_type(8))) __bf16 bf16x8;

__device__ __forceinline__ short f2bf(float x) {
    unsigned u = __float_as_uint(x);
    unsigned r = (u + 0x7fffu + ((u >> 16) & 1u)) >> 16;   // round-to-nearest-even
    return (short)r;
}
__device__ __forceinline__ float bf2f(short s) {
    return __uint_as_float(((unsigned)(unsigned short)s) << 16);
}

// ---------------- fused prep: weight packing + x split + deg zero ----------
// block ranges: [0,16) pack conv1, [16,32) pack conv2, [32,48) pack uv,
// [48, 48+DEGB) zero deg, [48+DEGB, ...) split x
__device__ __forceinline__ void pack_conv_body(const float* __restrict__ Wl,
                                               const float* __restrict__ Wr,
                                               short* __restrict__ Bh,
                                               short* __restrict__ Bl, int idx) {
    // idx in [0, 8*8*64)
    int l = idx & 63;
    int t = (idx >> 6) & 7;
    int s = idx >> 9;
    int n = t * 16 + (l & 15);
    int kbase = s * 32 + (l >> 4) * 8;
    s16x8 h, lo;
    #pragma unroll
    for (int j = 0; j < 8; ++j) {
        int k = kbase + j;
        float v = (k < 128) ? Wl[n * 128 + k] : Wr[n * 128 + (k - 128)];
        short hs = f2bf(v);
        h[j] = hs;
        lo[j] = f2bf(v - bf2f(hs));
    }
    ((s16x8*)Bh)[idx] = h;
    ((s16x8*)Bl)[idx] = lo;
}

__device__ __forceinline__ void pack_uv_body(const float* __restrict__ Wm1,
                                             short* __restrict__ Bh,
                                             short* __restrict__ Bl, int idx) {
    // idx in [0, 4*16*64)
    int l = idx & 63;
    int t = (idx >> 6) & 15;
    int s = idx >> 10;
    int np = t * 16 + (l & 15);
    int kbase = s * 32 + (l >> 4) * 8;
    s16x8 h, lo;
    #pragma unroll
    for (int j = 0; j < 8; ++j) {
        int k = kbase + j;
        float v = (np < 128) ? Wm1[np * 272 + k] : Wm1[(np - 128) * 272 + 128 + k];
        short hs = f2bf(v);
        h[j] = hs;
        lo[j] = f2bf(v - bf2f(hs));
    }
    ((s16x8*)Bh)[idx] = h;
    ((s16x8*)Bl)[idx] = lo;
}

__global__ void k_prep(const float* __restrict__ x,
                       const float* __restrict__ W1_l, const float* __restrict__ W1_r,
                       const float* __restrict__ W2_l, const float* __restrict__ W2_r,
                       const float* __restrict__ Wm1,
                       short* __restrict__ Wc1h, short* __restrict__ Wc1l,
                       short* __restrict__ Wc2h, short* __restrict__ Wc2l,
                       short* __restrict__ Buvh, short* __restrict__ Buvl,
                       short* __restrict__ Xh, short* __restrict__ Xl,
                       int* __restrict__ deg, int n_nodes, int degb, int nsplit4) {
    int b = blockIdx.x;
    int tid = threadIdx.x;
    if (b < 16) {
        pack_conv_body(W1_l, W1_r, Wc1h, Wc1l, b * 256 + tid);
    } else if (b < 32) {
        pack_conv_body(W2_l, W2_r, Wc2h, Wc2l, (b - 16) * 256 + tid);
    } else if (b < 48) {
        pack_uv_body(Wm1, Buvh, Buvl, (b - 32) * 256 + tid);
    } else if (b < 48 + degb) {
        int i = (b - 48) * 256 + tid;
        if (i < n_nodes) deg[i] = 0;
    } else {
        int i = (b - 48 - degb) * 256 + tid;
        if (i < nsplit4) {
            float4 v = ((const float4*)x)[i];
            s16x4 h, l;
            h[0] = f2bf(v.x); l[0] = f2bf(v.x - bf2f(h[0]));
            h[1] = f2bf(v.y); l[1] = f2bf(v.y - bf2f(h[1]));
            h[2] = f2bf(v.z); l[2] = f2bf(v.z - bf2f(h[2]));
            h[3] = f2bf(v.w); l[3] = f2bf(v.w - bf2f(h[3]));
            ((s16x4*)Xh)[i] = h;
            ((s16x4*)Xl)[i] = l;
        }
    }
}

// ---------------- CSR construction ----------------
__global__ void k_deg(const int* __restrict__ dst, int* __restrict__ deg, int n_edges) {
    for (int e = blockIdx.x * blockDim.x + threadIdx.x; e < n_edges; e += gridDim.x * blockDim.x)
        atomicAdd(&deg[dst[e]], 1);
}

// block-local exclusive scan; part[b] = block total
__global__ __launch_bounds__(1024) void k_scan_blk(const int* __restrict__ deg,
                                                   int* __restrict__ row_start,
                                                   int* __restrict__ part, int n) {
    __shared__ int wsum[16];
    int tid = threadIdx.x;
    int lane = tid & 63;
    int w = tid >> 6;
    int i = blockIdx.x * 1024 + tid;
    int v = (i < n) ? deg[i] : 0;
    int s = v;
    #pragma unroll
    for (int off = 1; off < 64; off <<= 1) {
        int t = __shfl_up(s, off, 64);
        if (lane >= off) s += t;
    }
    if (lane == 63) wsum[w] = s;
    __syncthreads();
    if (w == 0) {
        int ws = (lane < 16) ? wsum[lane] : 0;
        #pragma unroll
        for (int off = 1; off < 16; off <<= 1) {
            int t = __shfl_up(ws, off, 64);
            if (lane >= off) ws += t;
        }
        if (lane < 16) wsum[lane] = ws;
    }
    __syncthreads();
    int incl = s + ((w > 0) ? wsum[w - 1] : 0);
    if (i < n) row_start[i] = incl - v;
    if (tid == 1023) part[blockIdx.x] = incl;
}

// single-wave scan of block partials (P <= 64)
__global__ void k_scan_top(int* __restrict__ part, int* __restrict__ row_start,
                           int P, int n) {
    int lane = threadIdx.x;
    int v = (lane < P) ? part[lane] : 0;
    int s = v;
    #pragma unroll
    for (int off = 1; off < 64; off <<= 1) {
        int t = __shfl_up(s, off, 64);
        if (lane >= off) s += t;
    }
    if (lane < P) part[lane] = s - v;
    if (lane == P - 1) row_start[n] = s;
}

__global__ __launch_bounds__(1024) void k_scan_add(int* __restrict__ row_start,
                                                   int* __restrict__ cursor,
                                                   const int* __restrict__ part, int n) {
    int i = blockIdx.x * 1024 + threadIdx.x;
    if (i < n) {
        int r = row_start[i] + part[blockIdx.x];
        row_start[i] = r;
        cursor[i] = r;
    }
}

__global__ void k_fill(const int* __restrict__ src, const int* __restrict__ dst,
                       int* __restrict__ cursor, int* __restrict__ csr, int n_edges) {
    for (int e = blockIdx.x * blockDim.x + threadIdx.x; e < n_edges; e += gridDim.x * blockDim.x) {
        int d = dst[e];
        int p = atomicAdd(&cursor[d], 1);
        csr[p] = src[e];
    }
}

// ---------------- mean aggregation (fp32 input) -> split hi/lo tables -------
// one 64-lane wave per node; lane owns features 2*lane, 2*lane+1; 2x unroll
__global__ __launch_bounds__(256) void k_agg_f32(const float* __restrict__ feat,
                                                 const int* __restrict__ row_start,
                                                 const int* __restrict__ csr,
                                                 short* __restrict__ Mh,
                                                 short* __restrict__ Ml, int n_nodes) {
    int wave = (blockIdx.x * 256 + threadIdx.x) >> 6;
    if (wave >= n_nodes) return;
    int lane = threadIdx.x & 63;
    int s = row_start[wave], e = row_start[wave + 1];
    const float2* f2p = (const float2*)feat;
    float ax = 0.f, ay = 0.f;
    int j = s;
    for (; j + 1 < e; j += 2) {
        int nb0 = csr[j];
        int nb1 = csr[j + 1];
        float2 v0 = f2p[(size_t)nb0 * 64 + lane];
        float2 v1 = f2p[(size_t)nb1 * 64 + lane];
        ax += v0.x + v1.x;
        ay += v0.y + v1.y;
    }
    if (j < e) {
        int nb = csr[j];
        float2 v = f2p[(size_t)nb * 64 + lane];
        ax += v.x; ay += v.y;
    }
    float inv = (e > s) ? 1.0f / (float)(e - s) : 0.0f;
    float m0 = ax * inv, m1 = ay * inv;
    short h0 = f2bf(m0), l0 = f2bf(m0 - bf2f(h0));
    short h1 = f2bf(m1), l1 = f2bf(m1 - bf2f(h1));
    ((ushort2*)Mh)[wave * 64 + lane] = make_ushort2((unsigned short)h0, (unsigned short)h1);
    ((ushort2*)Ml)[wave * 64 + lane] = make_ushort2((unsigned short)l0, (unsigned short)l1);
}

// ---------------- mean aggregation from split hi/lo tables (lane-split) -----
// lanes 0..31 read the HI table row, lanes 32..63 the LO row (one 8B load/lane),
// combine via one shfl_xor(32). lane-group owns feats 4*l32 .. 4*l32+3.
__global__ __launch_bounds__(256) void k_agg_sp(const short* __restrict__ Fh,
                                                const short* __restrict__ Fl,
                                                const int* __restrict__ row_start,
                                                const int* __restrict__ csr,
                                                short* __restrict__ Mh,
                                                short* __restrict__ Ml, int n_nodes) {
    int wave = (blockIdx.x * 256 + threadIdx.x) >> 6;
    if (wave >= n_nodes) return;
    int lane = threadIdx.x & 63;
    int half = lane >> 5;
    int l32 = lane & 31;
    const s16x4* base = (const s16x4*)(half ? Fl : Fh);
    int s = row_start[wave], e = row_start[wave + 1];
    float a0 = 0.f, a1 = 0.f, a2 = 0.f, a3 = 0.f;
    int j = s;
    for (; j + 1 < e; j += 2) {
        int nb0 = csr[j];
        int nb1 = csr[j + 1];
        s16x4 q0 = base[(size_t)nb0 * 32 + l32];
        s16x4 q1 = base[(size_t)nb1 * 32 + l32];
        a0 += bf2f(q0[0]) + bf2f(q1[0]);
        a1 += bf2f(q0[1]) + bf2f(q1[1]);
        a2 += bf2f(q0[2]) + bf2f(q1[2]);
        a3 += bf2f(q0[3]) + bf2f(q1[3]);
    }
    if (j < e) {
        int nb = csr[j];
        s16x4 q = base[(size_t)nb * 32 + l32];
        a0 += bf2f(q[0]); a1 += bf2f(q[1]); a2 += bf2f(q[2]); a3 += bf2f(q[3]);
    }
    // combine hi-half + lo-half accumulators
    a0 += __shfl_xor(a0, 32, 64);
    a1 += __shfl_xor(a1, 32, 64);
    a2 += __shfl_xor(a2, 32, 64);
    a3 += __shfl_xor(a3, 32, 64);
    float inv = (e > s) ? 1.0f / (float)(e - s) : 0.0f;
    float m0 = a0 * inv, m1 = a1 * inv, m2 = a2 * inv, m3 = a3 * inv;
    short h0 = f2bf(m0), h1 = f2bf(m1), h2 = f2bf(m2), h3 = f2bf(m3);
    s16x4 o;
    if (half == 0) {
        o[0] = h0; o[1] = h1; o[2] = h2; o[3] = h3;
    } else {
        o[0] = f2bf(m0 - bf2f(h0));
        o[1] = f2bf(m1 - bf2f(h1));
        o[2] = f2bf(m2 - bf2f(h2));
        o[3] = f2bf(m3 - bf2f(h3));
    }
    ((s16x4*)(half ? Ml : Mh))[(size_t)wave * 32 + l32] = o;
}

// ---------------- SAGE conv via split-bf16 MFMA ----------------
// 32 nodes/block, 256 thr (4 waves x 2 ntiles). A=[mean|root] K=256 (8 ksteps).
__global__ __launch_bounds__(256, 4) void k_convm(
    const short* __restrict__ Mh, const short* __restrict__ Ml,
    const short* __restrict__ Rh, const short* __restrict__ Rl,
    const short* __restrict__ Bh, const short* __restrict__ Bl,
    const float* __restrict__ bias, short* __restrict__ Oh, short* __restrict__ Ol,
    int n_nodes) {
    __shared__ __align__(16) short Ah[32][264];
    __shared__ __align__(16) short Al[32][264];
    int tid = threadIdx.x;
    int node0 = blockIdx.x * 32;
    const s16x8* Mh8 = (const s16x8*)Mh;
    const s16x8* Ml8 = (const s16x8*)Ml;
    const s16x8* Rh8 = (const s16x8*)Rh;
    const s16x8* Rl8 = (const s16x8*)Rl;
    for (int i = tid; i < 32 * 32; i += 256) {
        int row = i >> 5, grp = i & 31;
        int node = node0 + row;
        s16x8 vh = (s16x8)0, vl = (s16x8)0;
        if (node < n_nodes) {
            vh = (grp < 16) ? Mh8[node * 16 + grp] : Rh8[node * 16 + (grp - 16)];
            vl = (grp < 16) ? Ml8[node * 16 + grp] : Rl8[node * 16 + (grp - 16)];
        }
        *(s16x8*)&Ah[row][grp * 8] = vh;
        *(s16x8*)&Al[row][grp * 8] = vl;
    }
    __syncthreads();

    int lane = tid & 63;
    int w = tid >> 6;
    int rowid = lane & 15;
    int g = lane >> 4;
    int t0 = w * 2;

    f32x4 acc[2][2];
    acc[0][0] = (f32x4)0.f; acc[0][1] = (f32x4)0.f;
    acc[1][0] = (f32x4)0.f; acc[1][1] = (f32x4)0.f;

    const bf16x8* Bh8 = (const bf16x8*)Bh;
    const bf16x8* Bl8 = (const bf16x8*)Bl;
    bf16x8 bh0 = Bh8[t0 * 64 + lane];
    bf16x8 bh1 = Bh8[(t0 + 1) * 64 + lane];
    bf16x8 bl0 = Bl8[t0 * 64 + lane];
    bf16x8 bl1 = Bl8[(t0 + 1) * 64 + lane];

    #pragma unroll
    for (int s = 0; s < 8; ++s) {
        bf16x8 nh0 = bh0, nh1 = bh1, nl0 = bl0, nl1 = bl1;
        if (s < 7) {
            nh0 = Bh8[((s + 1) * 8 + t0) * 64 + lane];
            nh1 = Bh8[((s + 1) * 8 + t0 + 1) * 64 + lane];
            nl0 = Bl8[((s + 1) * 8 + t0) * 64 + lane];
            nl1 = Bl8[((s + 1) * 8 + t0 + 1) * 64 + lane];
        }
        int kf = s * 32 + g * 8;
        bf16x8 a_h[2], a_l[2];
        #pragma unroll
        for (int m = 0; m < 2; ++m) {
            a_h[m] = *(const bf16x8*)&Ah[m * 16 + rowid][kf];
            a_l[m] = *(const bf16x8*)&Al[m * 16 + rowid][kf];
        }
        #pragma unroll
        for (int m = 0; m < 2; ++m) {
            acc[m][0] = __builtin_amdgcn_mfma_f32_16x16x32_bf16(a_h[m], bh0, acc[m][0], 0, 0, 0);
            acc[m][1] = __builtin_amdgcn_mfma_f32_16x16x32_bf16(a_h[m], bh1, acc[m][1], 0, 0, 0);
            acc[m][0] = __builtin_amdgcn_mfma_f32_16x16x32_bf16(a_l[m], bh0, acc[m][0], 0, 0, 0);
            acc[m][1] = __builtin_amdgcn_mfma_f32_16x16x32_bf16(a_l[m], bh1, acc[m][1], 0, 0, 0);
            acc[m][0] = __builtin_amdgcn_mfma_f32_16x16x32_bf16(a_h[m], bl0, acc[m][0], 0, 0, 0);
            acc[m][1] = __builtin_amdgcn_mfma_f32_16x16x32_bf16(a_h[m], bl1, acc[m][1], 0, 0, 0);
        }
        bh0 = nh0; bh1 = nh1; bl0 = nl0; bl1 = nl1;
    }

    int n0 = w * 32 + rowid;
    int n1 = n0 + 16;
    float b_0 = bias[n0], b_1 = bias[n1];
    unsigned short* OhU = (unsigned short*)Oh;
    unsigned short* OlU = (unsigned short*)Ol;
    #pragma unroll
    for (int m = 0; m < 2; ++m) {
        int node = node0 + m * 16 + g * 4;
        #pragma unroll
        for (int r = 0; r < 4; ++r) {
            if (node + r < n_nodes) {
                float v0 = fmaxf(acc[m][0][r] + b_0, 0.f);
                float v1 = fmaxf(acc[m][1][r] + b_1, 0.f);
                short h0 = f2bf(v0), l0 = f2bf(v0 - bf2f(h0));
                short h1 = f2bf(v1), l1 = f2bf(v1 - bf2f(h1));
                OhU[(node + r) * 128 + n0] = (unsigned short)h0;
                OlU[(node + r) * 128 + n0] = (unsigned short)l0;
                OhU[(node + r) * 128 + n1] = (unsigned short)h1;
                OlU[(node + r) * 128 + n1] = (unsigned short)l1;
            }
        }
    }
}

// ---------------- UV GEMM: [U|V] = h2 @ [Wm1_s; Wm1_d]^T (K=128) -----------
__global__ __launch_bounds__(256, 4) void k_guv(
    const short* __restrict__ H2h, const short* __restrict__ H2l,
    const short* __restrict__ Bh, const short* __restrict__ Bl,
    float* __restrict__ U, float* __restrict__ V, int n_nodes) {
    __shared__ __align__(16) short Ah[32][136];
    __shared__ __align__(16) short Al[32][136];
    int tid = threadIdx.x;
    int node0 = blockIdx.x * 32;
    const s16x8* Hh8 = (const s16x8*)H2h;
    const s16x8* Hl8 = (const s16x8*)H2l;
    for (int i = tid; i < 32 * 16; i += 256) {
        int row = i >> 4, grp = i & 15;
        int node = node0 + row;
        s16x8 vh = (s16x8)0, vl = (s16x8)0;
        if (node < n_nodes) {
            vh = Hh8[node * 16 + grp];
            vl = Hl8[node * 16 + grp];
        }
        *(s16x8*)&Ah[row][grp * 8] = vh;
        *(s16x8*)&Al[row][grp * 8] = vl;
    }
    __syncthreads();

    int lane = tid & 63;
    int w = tid >> 6;
    int rowid = lane & 15;
    int g = lane >> 4;
    int t0 = w * 4;

    f32x4 acc[2][4];
    #pragma unroll
    for (int m = 0; m < 2; ++m)
        #pragma unroll
        for (int q = 0; q < 4; ++q) acc[m][q] = (f32x4)0.f;

    const bf16x8* Bh8 = (const bf16x8*)Bh;
    const bf16x8* Bl8 = (const bf16x8*)Bl;

    #pragma unroll
    for (int s = 0; s < 4; ++s) {
        bf16x8 bh[4], bl[4];
        #pragma unroll
        for (int q = 0; q < 4; ++q) {
            bh[q] = Bh8[(s * 16 + t0 + q) * 64 + lane];
            bl[q] = Bl8[(s * 16 + t0 + q) * 64 + lane];
        }
        int kf = s * 32 + g * 8;
        bf16x8 a_h[2], a_l[2];
        #pragma unroll
        for (int m = 0; m < 2; ++m) {
            a_h[m] = *(const bf16x8*)&Ah[m * 16 + rowid][kf];
            a_l[m] = *(const bf16x8*)&Al[m * 16 + rowid][kf];
        }
        #pragma unroll
        for (int m = 0; m < 2; ++m) {
            #pragma unroll
            for (int q = 0; q < 4; ++q) {
                acc[m][q] = __builtin_amdgcn_mfma_f32_16x16x32_bf16(a_h[m], bh[q], acc[m][q], 0, 0, 0);
                acc[m][q] = __builtin_amdgcn_mfma_f32_16x16x32_bf16(a_l[m], bh[q], acc[m][q], 0, 0, 0);
                acc[m][q] = __builtin_amdgcn_mfma_f32_16x16x32_bf16(a_h[m], bl[q], acc[m][q], 0, 0, 0);
            }
        }
    }

    float* dstbase = (w < 2) ? U : V;
    int cb = (w & 1) * 64 + rowid;
    #pragma unroll
    for (int m = 0; m < 2; ++m) {
        int node = node0 + m * 16 + g * 4;
        #pragma unroll
        for (int q = 0; q < 4; ++q) {
            int col = cb + q * 16;
            #pragma unroll
            for (int r = 0; r < 4; ++r) {
                if (node + r < n_nodes)
                    dstbase[(node + r) * 128 + col] = acc[m][q][r];
            }
        }
    }
}

// ---------------- streaming edge kernel (reg-friendly, 2-edge unroll) -------
// wave handles edges e, e+1: out = wm2 . relu(U[s] + V[d] + Wa@attr + bm1) + bm2
__global__ __launch_bounds__(256, 4) void k_edge(
    const float* __restrict__ U, const float* __restrict__ V,
    const int* __restrict__ ps, const int* __restrict__ pd,
    const float* __restrict__ attr, const float* __restrict__ Wm1,
    const float* __restrict__ bm1, const float* __restrict__ wm2,
    const float* __restrict__ bm2, float* __restrict__ outp, int n_edges) {
    int lane = threadIdx.x & 63;
    int wid = (blockIdx.x * 256 + threadIdx.x) >> 6;
    int nw = (gridDim.x * 256) >> 6;

    int j0 = 2 * lane;
    const float* wr0 = &Wm1[j0 * 272 + 256];
    const float* wr1 = &Wm1[(j0 + 1) * 272 + 256];
    float4 wa0a = *(const float4*)&wr0[0];
    float4 wa0b = *(const float4*)&wr0[4];
    float4 wa0c = *(const float4*)&wr0[8];
    float4 wa0d = *(const float4*)&wr0[12];
    float4 wa1a = *(const float4*)&wr1[0];
    float4 wa1b = *(const float4*)&wr1[4];
    float4 wa1c = *(const float4*)&wr1[8];
    float4 wa1d = *(const float4*)&wr1[12];
    float bb0 = bm1[j0], bb1 = bm1[j0 + 1];
    float wm0 = wm2[j0], wmv1 = wm2[j0 + 1];
    float bm2v = bm2[0];

    const float2* U2 = (const float2*)U;
    const float2* V2 = (const float2*)V;
    const float4* at4 = (const float4*)attr;

    for (int e = wid * 2; e < n_edges; e += 2 * nw) {
        int e1 = e + 1;
        bool has1 = (e1 < n_edges);
        int e1c = has1 ? e1 : e;
        int s0 = ps[e],   d0 = pd[e];
        int s1 = ps[e1c], d1 = pd[e1c];
        float2 u0 = U2[(size_t)s0 * 64 + lane];
        float2 v0 = V2[(size_t)d0 * 64 + lane];
        float2 u1 = U2[(size_t)s1 * 64 + lane];
        float2 v1 = V2[(size_t)d1 * 64 + lane];
        float4 a00 = at4[(size_t)e * 4 + 0];
        float4 a01 = at4[(size_t)e * 4 + 1];
        float4 a02 = at4[(size_t)e * 4 + 2];
        float4 a03 = at4[(size_t)e * 4 + 3];
        float4 a10 = at4[(size_t)e1c * 4 + 0];
        float4 a11 = at4[(size_t)e1c * 4 + 1];
        float4 a12 = at4[(size_t)e1c * 4 + 2];
        float4 a13 = at4[(size_t)e1c * 4 + 3];

        float t00 = wa0a.x * a00.x + wa0a.y * a00.y + wa0a.z * a00.z + wa0a.w * a00.w
                  + wa0b.x * a01.x + wa0b.y * a01.y + wa0b.z * a01.z + wa0b.w * a01.w
                  + wa0c.x * a02.x + wa0c.y * a02.y + wa0c.z * a02.z + wa0c.w * a02.w
                  + wa0d.x * a03.x + wa0d.y * a03.y + wa0d.z * a03.z + wa0d.w * a03.w;
        float t01 = wa1a.x * a00.x + wa1a.y * a00.y + wa1a.z * a00.z + wa1a.w * a00.w
                  + wa1b.x * a01.x + wa1b.y * a01.y + wa1b.z * a01.z + wa1b.w * a01.w
                  + wa1c.x * a02.x + wa1c.y * a02.y + wa1c.z * a02.z + wa1c.w * a02.w
                  + wa1d.x * a03.x + wa1d.y * a03.y + wa1d.z * a03.z + wa1d.w * a03.w;
        float t10 = wa0a.x * a10.x + wa0a.y * a10.y + wa0a.z * a10.z + wa0a.w * a10.w
                  + wa0b.x * a11.x + wa0b.y * a11.y + wa0b.z * a11.z + wa0b.w * a11.w
                  + wa0c.x * a12.x + wa0c.y * a12.y + wa0c.z * a12.z + wa0c.w * a12.w
                  + wa0d.x * a13.x + wa0d.y * a13.y + wa0d.z * a13.z + wa0d.w * a13.w;
        float t11 = wa1a.x * a10.x + wa1a.y * a10.y + wa1a.z * a10.z + wa1a.w * a10.w
                  + wa1b.x * a11.x + wa1b.y * a11.y + wa1b.z * a11.z + wa1b.w * a11.w
                  + wa1c.x * a12.x + wa1c.y * a12.y + wa1c.z * a12.z + wa1c.w * a12.w
                  + wa1d.x * a13.x + wa1d.y * a13.y + wa1d.z * a13.z + wa1d.w * a13.w;

        float p0 = fmaxf(u0.x + v0.x + t00 + bb0, 0.f) * wm0
                 + fmaxf(u0.y + v0.y + t01 + bb1, 0.f) * wmv1;
        float p1 = fmaxf(u1.x + v1.x + t10 + bb0, 0.f) * wm0
                 + fmaxf(u1.y + v1.y + t11 + bb1, 0.f) * wmv1;
        #pragma unroll
        for (int m = 32; m >= 1; m >>= 1) {
            p0 += __shfl_xor(p0, m, 64);
            p1 += __shfl_xor(p1, m, 64);
        }
        if (lane == 0) outp[e] = p0 + bm2v;
        if (lane == 1 && has1) outp[e1] = p1 + bm2v;
    }
}

extern "C" void kernel_launch(void* const* d_in, const int* in_sizes, int n_in,
                              void* d_out, int out_size, void* d_ws, size_t ws_size,
                              hipStream_t stream) {
    const float* x     = (const float*)d_in[0];
    const int*   mp    = (const int*)d_in[1];
    const int*   pe    = (const int*)d_in[2];
    const float* attr  = (const float*)d_in[3];
    const float* W1_l  = (const float*)d_in[4];
    const float* b1    = (const float*)d_in[5];
    const float* W1_r  = (const float*)d_in[6];
    const float* W2_l  = (const float*)d_in[7];
    const float* b2    = (const float*)d_in[8];
    const float* W2_r  = (const float*)d_in[9];
    const float* Wm1   = (const float*)d_in[10];
    const float* bm1   = (const float*)d_in[11];
    const float* Wm2   = (const float*)d_in[12];
    const float* bm2   = (const float*)d_in[13];
    float* out = (float*)d_out;

    const int n_nodes = in_sizes[0] / HIDDEN;   // 50000
    const int n_mp    = in_sizes[1] / 2;        // 800000
    const int n_pred  = in_sizes[2] / 2;        // 400000

    const int* mp_src = mp;
    const int* mp_dst = mp + n_mp;
    const int* p_src  = pe;
    const int* p_dst  = pe + n_pred;

    char* ws = (char*)d_ws;
    size_t off = 0;
    auto alloc = [&](size_t bytes) -> void* {
        void* p = ws + off;
        off += (bytes + 255) & ~(size_t)255;
        return p;
    };
    short* Wc1h = (short*)alloc(8 * 8 * 64 * 8 * sizeof(short));
    short* Wc1l = (short*)alloc(8 * 8 * 64 * 8 * sizeof(short));
    short* Wc2h = (short*)alloc(8 * 8 * 64 * 8 * sizeof(short));
    short* Wc2l = (short*)alloc(8 * 8 * 64 * 8 * sizeof(short));
    short* Buvh = (short*)alloc(4 * 16 * 64 * 8 * sizeof(short));
    short* Buvl = (short*)alloc(4 * 16 * 64 * 8 * sizeof(short));
    int*   deg    = (int*)alloc((size_t)n_nodes * sizeof(int));
    int*   rowst  = (int*)alloc(((size_t)n_nodes + 1) * sizeof(int));
    int*   cursor = (int*)alloc((size_t)n_nodes * sizeof(int));
    int*   part   = (int*)alloc(64 * sizeof(int));
    int*   csr    = (int*)alloc((size_t)n_mp * sizeof(int));
    short* Xh  = (short*)alloc((size_t)n_nodes * HIDDEN * sizeof(short));
    short* Xl  = (short*)alloc((size_t)n_nodes * HIDDEN * sizeof(short));
    short* Mh  = (short*)alloc((size_t)n_nodes * HIDDEN * sizeof(short));
    short* Ml  = (short*)alloc((size_t)n_nodes * HIDDEN * sizeof(short));
    short* H1h = (short*)alloc((size_t)n_nodes * HIDDEN * sizeof(short));
    short* H1l = (short*)alloc((size_t)n_nodes * HIDDEN * sizeof(short));
    short* H2h = (short*)alloc((size_t)n_nodes * HIDDEN * sizeof(short));
    short* H2l = (short*)alloc((size_t)n_nodes * HIDDEN * sizeof(short));
    float* Ubuf = (float*)alloc((size_t)n_nodes * HIDDEN * sizeof(float));
    float* Vbuf = (float*)alloc((size_t)n_nodes * HIDDEN * sizeof(float));
    (void)ws_size; (void)n_in; (void)out_size;

    const int P = (n_nodes + 1023) / 1024;        // 49 scan blocks (<=64)
    const int degb = (n_nodes + 255) / 256;       // deg-zero blocks
    const int nsplit4 = n_nodes * 32;             // float4 groups in x
    const int splitb = (nsplit4 + 255) / 256;

    // fused prep: packs + deg zero + x split (replaces 4 launches + memset)
    k_prep<<<48 + degb + splitb, 256, 0, stream>>>(x, W1_l, W1_r, W2_l, W2_r, Wm1,
                                                   Wc1h, Wc1l, Wc2h, Wc2l, Buvh, Buvl,
                                                   Xh, Xl, deg, n_nodes, degb, nsplit4);

    // CSR build
    k_deg<<<(n_mp + 255) / 256, 256, 0, stream>>>(mp_dst, deg, n_mp);
    k_scan_blk<<<P, 1024, 0, stream>>>(deg, rowst, part, n_nodes);
    k_scan_top<<<1, 64, 0, stream>>>(part, rowst, P, n_nodes);
    k_scan_add<<<P, 1024, 0, stream>>>(rowst, cursor, part, n_nodes);
    k_fill<<<(n_mp + 255) / 256, 256, 0, stream>>>(mp_src, mp_dst, cursor, csr, n_mp);

    // conv1
    k_agg_f32<<<(n_nodes + 3) / 4, 256, 0, stream>>>(x, rowst, csr, Mh, Ml, n_nodes);
    k_convm<<<(n_nodes + 31) / 32, 256, 0, stream>>>(Mh, Ml, Xh, Xl, Wc1h, Wc1l, b1,
                                                     H1h, H1l, n_nodes);
    // conv2
    k_agg_sp<<<(n_nodes + 3) / 4, 256, 0, stream>>>(H1h, H1l, rowst, csr, Mh, Ml, n_nodes);
    k_convm<<<(n_nodes + 31) / 32, 256, 0, stream>>>(Mh, Ml, H1h, H1l, Wc2h, Wc2l, b2,
                                                     H2h, H2l, n_nodes);

    // UV GEMM + streaming edge MLP
    k_guv<<<(n_nodes + 31) / 32, 256, 0, stream>>>(H2h, H2l, Buvh, Buvl, Ubuf, Vbuf, n_nodes);
    k_edge<<<2048, 256, 0, stream>>>(Ubuf, Vbuf, p_src, p_dst, attr, Wm1,
                                     bm1, Wm2, bm2, out, n_pred);
}

// Round 9
// 552.035 us; speedup vs baseline: 1.1008x; 1.1008x over previous
//
#include <hip/hip_runtime.h>
#include <hip/hip_bf16.h>

#define HIDDEN 128

typedef __attribute__((ext_vector_type(8))) short s16x8;
typedef __attribute__((ext_vector_type(4))) short s16x4;
typedef __attribute__((ext_vector_type(4))) float f32x4;
typedef __attribute__((ext_vector_type(8))) __bf16 bf16x8;

__device__ __forceinline__ short f2bf(float x) {
    unsigned u = __float_as_uint(x);
    unsigned r = (u + 0x7fffu + ((u >> 16) & 1u)) >> 16;   // round-to-nearest-even
    return (short)r;
}
__device__ __forceinline__ float bf2f(short s) {
    return __uint_as_float(((unsigned)(unsigned short)s) << 16);
}

// ---------------- fused prep: weight packing + x split + deg zero ----------
__device__ __forceinline__ void pack_conv_body(const float* __restrict__ Wl,
                                               const float* __restrict__ Wr,
                                               short* __restrict__ Bh,
                                               short* __restrict__ Bl, int idx) {
    int l = idx & 63;
    int t = (idx >> 6) & 7;
    int s = idx >> 9;
    int n = t * 16 + (l & 15);
    int kbase = s * 32 + (l >> 4) * 8;
    s16x8 h, lo;
    #pragma unroll
    for (int j = 0; j < 8; ++j) {
        int k = kbase + j;
        float v = (k < 128) ? Wl[n * 128 + k] : Wr[n * 128 + (k - 128)];
        short hs = f2bf(v);
        h[j] = hs;
        lo[j] = f2bf(v - bf2f(hs));
    }
    ((s16x8*)Bh)[idx] = h;
    ((s16x8*)Bl)[idx] = lo;
}

__device__ __forceinline__ void pack_uv_body(const float* __restrict__ Wm1,
                                             short* __restrict__ Bh,
                                             short* __restrict__ Bl, int idx) {
    int l = idx & 63;
    int t = (idx >> 6) & 15;
    int s = idx >> 10;
    int np = t * 16 + (l & 15);
    int kbase = s * 32 + (l >> 4) * 8;
    s16x8 h, lo;
    #pragma unroll
    for (int j = 0; j < 8; ++j) {
        int k = kbase + j;
        float v = (np < 128) ? Wm1[np * 272 + k] : Wm1[(np - 128) * 272 + 128 + k];
        short hs = f2bf(v);
        h[j] = hs;
        lo[j] = f2bf(v - bf2f(hs));
    }
    ((s16x8*)Bh)[idx] = h;
    ((s16x8*)Bl)[idx] = lo;
}

__global__ void k_prep(const float* __restrict__ x,
                       const float* __restrict__ W1_l, const float* __restrict__ W1_r,
                       const float* __restrict__ W2_l, const float* __restrict__ W2_r,
                       const float* __restrict__ Wm1,
                       short* __restrict__ Wc1h, short* __restrict__ Wc1l,
                       short* __restrict__ Wc2h, short* __restrict__ Wc2l,
                       short* __restrict__ Buvh, short* __restrict__ Buvl,
                       short* __restrict__ Xh, short* __restrict__ Xl,
                       int* __restrict__ deg, int n_nodes, int degb, int nsplit4) {
    int b = blockIdx.x;
    int tid = threadIdx.x;
    if (b < 16) {
        pack_conv_body(W1_l, W1_r, Wc1h, Wc1l, b * 256 + tid);
    } else if (b < 32) {
        pack_conv_body(W2_l, W2_r, Wc2h, Wc2l, (b - 16) * 256 + tid);
    } else if (b < 48) {
        pack_uv_body(Wm1, Buvh, Buvl, (b - 32) * 256 + tid);
    } else if (b < 48 + degb) {
        int i = (b - 48) * 256 + tid;
        if (i < n_nodes) deg[i] = 0;
    } else {
        int i = (b - 48 - degb) * 256 + tid;
        if (i < nsplit4) {
            float4 v = ((const float4*)x)[i];
            s16x4 h, l;
            h[0] = f2bf(v.x); l[0] = f2bf(v.x - bf2f(h[0]));
            h[1] = f2bf(v.y); l[1] = f2bf(v.y - bf2f(h[1]));
            h[2] = f2bf(v.z); l[2] = f2bf(v.z - bf2f(h[2]));
            h[3] = f2bf(v.w); l[3] = f2bf(v.w - bf2f(h[3]));
            ((s16x4*)Xh)[i] = h;
            ((s16x4*)Xl)[i] = l;
        }
    }
}

// ---------------- CSR construction ----------------
__global__ void k_deg(const int* __restrict__ dst, int* __restrict__ deg, int n_edges) {
    for (int e = blockIdx.x * blockDim.x + threadIdx.x; e < n_edges; e += gridDim.x * blockDim.x)
        atomicAdd(&deg[dst[e]], 1);
}

__global__ __launch_bounds__(1024) void k_scan_blk(const int* __restrict__ deg,
                                                   int* __restrict__ row_start,
                                                   int* __restrict__ part, int n) {
    __shared__ int wsum[16];
    int tid = threadIdx.x;
    int lane = tid & 63;
    int w = tid >> 6;
    int i = blockIdx.x * 1024 + tid;
    int v = (i < n) ? deg[i] : 0;
    int s = v;
    #pragma unroll
    for (int off = 1; off < 64; off <<= 1) {
        int t = __shfl_up(s, off, 64);
        if (lane >= off) s += t;
    }
    if (lane == 63) wsum[w] = s;
    __syncthreads();
    if (w == 0) {
        int ws = (lane < 16) ? wsum[lane] : 0;
        #pragma unroll
        for (int off = 1; off < 16; off <<= 1) {
            int t = __shfl_up(ws, off, 64);
            if (lane >= off) ws += t;
        }
        if (lane < 16) wsum[lane] = ws;
    }
    __syncthreads();
    int incl = s + ((w > 0) ? wsum[w - 1] : 0);
    if (i < n) row_start[i] = incl - v;
    if (tid == 1023) part[blockIdx.x] = incl;
}

__global__ void k_scan_top(int* __restrict__ part, int* __restrict__ row_start,
                           int P, int n) {
    int lane = threadIdx.x;
    int v = (lane < P) ? part[lane] : 0;
    int s = v;
    #pragma unroll
    for (int off = 1; off < 64; off <<= 1) {
        int t = __shfl_up(s, off, 64);
        if (lane >= off) s += t;
    }
    if (lane < P) part[lane] = s - v;
    if (lane == P - 1) row_start[n] = s;
}

__global__ __launch_bounds__(1024) void k_scan_add(int* __restrict__ row_start,
                                                   int* __restrict__ cursor,
                                                   const int* __restrict__ part, int n) {
    int i = blockIdx.x * 1024 + threadIdx.x;
    if (i < n) {
        int r = row_start[i] + part[blockIdx.x];
        row_start[i] = r;
        cursor[i] = r;
    }
}

__global__ void k_fill(const int* __restrict__ src, const int* __restrict__ dst,
                       int* __restrict__ cursor, int* __restrict__ csr, int n_edges) {
    for (int e = blockIdx.x * blockDim.x + threadIdx.x; e < n_edges; e += gridDim.x * blockDim.x) {
        int d = dst[e];
        int p = atomicAdd(&cursor[d], 1);
        csr[p] = src[e];
    }
}

// ---------------- mean aggregation (fp32 input) -> split hi/lo tables -------
__global__ __launch_bounds__(256) void k_agg_f32(const float* __restrict__ feat,
                                                 const int* __restrict__ row_start,
                                                 const int* __restrict__ csr,
                                                 short* __restrict__ Mh,
                                                 short* __restrict__ Ml, int n_nodes) {
    int wave = (blockIdx.x * 256 + threadIdx.x) >> 6;
    if (wave >= n_nodes) return;
    int lane = threadIdx.x & 63;
    int s = row_start[wave], e = row_start[wave + 1];
    const float2* f2p = (const float2*)feat;
    float ax = 0.f, ay = 0.f;
    int j = s;
    for (; j + 1 < e; j += 2) {
        int nb0 = csr[j];
        int nb1 = csr[j + 1];
        float2 v0 = f2p[(size_t)nb0 * 64 + lane];
        float2 v1 = f2p[(size_t)nb1 * 64 + lane];
        ax += v0.x + v1.x;
        ay += v0.y + v1.y;
    }
    if (j < e) {
        int nb = csr[j];
        float2 v = f2p[(size_t)nb * 64 + lane];
        ax += v.x; ay += v.y;
    }
    float inv = (e > s) ? 1.0f / (float)(e - s) : 0.0f;
    float m0 = ax * inv, m1 = ay * inv;
    short h0 = f2bf(m0), l0 = f2bf(m0 - bf2f(h0));
    short h1 = f2bf(m1), l1 = f2bf(m1 - bf2f(h1));
    ((ushort2*)Mh)[wave * 64 + lane] = make_ushort2((unsigned short)h0, (unsigned short)h1);
    ((ushort2*)Ml)[wave * 64 + lane] = make_ushort2((unsigned short)l0, (unsigned short)l1);
}

// ---------------- mean aggregation from split hi/lo tables (lane-split) -----
__global__ __launch_bounds__(256) void k_agg_sp(const short* __restrict__ Fh,
                                                const short* __restrict__ Fl,
                                                const int* __restrict__ row_start,
                                                const int* __restrict__ csr,
                                                short* __restrict__ Mh,
                                                short* __restrict__ Ml, int n_nodes) {
    int wave = (blockIdx.x * 256 + threadIdx.x) >> 6;
    if (wave >= n_nodes) return;
    int lane = threadIdx.x & 63;
    int half = lane >> 5;
    int l32 = lane & 31;
    const s16x4* base = (const s16x4*)(half ? Fl : Fh);
    int s = row_start[wave], e = row_start[wave + 1];
    float a0 = 0.f, a1 = 0.f, a2 = 0.f, a3 = 0.f;
    int j = s;
    for (; j + 1 < e; j += 2) {
        int nb0 = csr[j];
        int nb1 = csr[j + 1];
        s16x4 q0 = base[(size_t)nb0 * 32 + l32];
        s16x4 q1 = base[(size_t)nb1 * 32 + l32];
        a0 += bf2f(q0[0]) + bf2f(q1[0]);
        a1 += bf2f(q0[1]) + bf2f(q1[1]);
        a2 += bf2f(q0[2]) + bf2f(q1[2]);
        a3 += bf2f(q0[3]) + bf2f(q1[3]);
    }
    if (j < e) {
        int nb = csr[j];
        s16x4 q = base[(size_t)nb * 32 + l32];
        a0 += bf2f(q[0]); a1 += bf2f(q[1]); a2 += bf2f(q[2]); a3 += bf2f(q[3]);
    }
    a0 += __shfl_xor(a0, 32, 64);
    a1 += __shfl_xor(a1, 32, 64);
    a2 += __shfl_xor(a2, 32, 64);
    a3 += __shfl_xor(a3, 32, 64);
    float inv = (e > s) ? 1.0f / (float)(e - s) : 0.0f;
    float m0 = a0 * inv, m1 = a1 * inv, m2 = a2 * inv, m3 = a3 * inv;
    short h0 = f2bf(m0), h1 = f2bf(m1), h2 = f2bf(m2), h3 = f2bf(m3);
    s16x4 o;
    if (half == 0) {
        o[0] = h0; o[1] = h1; o[2] = h2; o[3] = h3;
    } else {
        o[0] = f2bf(m0 - bf2f(h0));
        o[1] = f2bf(m1 - bf2f(h1));
        o[2] = f2bf(m2 - bf2f(h2));
        o[3] = f2bf(m3 - bf2f(h3));
    }
    ((s16x4*)(half ? Ml : Mh))[(size_t)wave * 32 + l32] = o;
}

// ---------------- SAGE conv via split-bf16 MFMA ----------------
__global__ __launch_bounds__(256, 4) void k_convm(
    const short* __restrict__ Mh, const short* __restrict__ Ml,
    const short* __restrict__ Rh, const short* __restrict__ Rl,
    const short* __restrict__ Bh, const short* __restrict__ Bl,
    const float* __restrict__ bias, short* __restrict__ Oh, short* __restrict__ Ol,
    int n_nodes) {
    __shared__ __align__(16) short Ah[32][264];
    __shared__ __align__(16) short Al[32][264];
    int tid = threadIdx.x;
    int node0 = blockIdx.x * 32;
    const s16x8* Mh8 = (const s16x8*)Mh;
    const s16x8* Ml8 = (const s16x8*)Ml;
    const s16x8* Rh8 = (const s16x8*)Rh;
    const s16x8* Rl8 = (const s16x8*)Rl;
    for (int i = tid; i < 32 * 32; i += 256) {
        int row = i >> 5, grp = i & 31;
        int node = node0 + row;
        s16x8 vh = (s16x8)0, vl = (s16x8)0;
        if (node < n_nodes) {
            vh = (grp < 16) ? Mh8[node * 16 + grp] : Rh8[node * 16 + (grp - 16)];
            vl = (grp < 16) ? Ml8[node * 16 + grp] : Rl8[node * 16 + (grp - 16)];
        }
        *(s16x8*)&Ah[row][grp * 8] = vh;
        *(s16x8*)&Al[row][grp * 8] = vl;
    }
    __syncthreads();

    int lane = tid & 63;
    int w = tid >> 6;
    int rowid = lane & 15;
    int g = lane >> 4;
    int t0 = w * 2;

    f32x4 acc[2][2];
    acc[0][0] = (f32x4)0.f; acc[0][1] = (f32x4)0.f;
    acc[1][0] = (f32x4)0.f; acc[1][1] = (f32x4)0.f;

    const bf16x8* Bh8 = (const bf16x8*)Bh;
    const bf16x8* Bl8 = (const bf16x8*)Bl;
    bf16x8 bh0 = Bh8[t0 * 64 + lane];
    bf16x8 bh1 = Bh8[(t0 + 1) * 64 + lane];
    bf16x8 bl0 = Bl8[t0 * 64 + lane];
    bf16x8 bl1 = Bl8[(t0 + 1) * 64 + lane];

    #pragma unroll
    for (int s = 0; s < 8; ++s) {
        bf16x8 nh0 = bh0, nh1 = bh1, nl0 = bl0, nl1 = bl1;
        if (s < 7) {
            nh0 = Bh8[((s + 1) * 8 + t0) * 64 + lane];
            nh1 = Bh8[((s + 1) * 8 + t0 + 1) * 64 + lane];
            nl0 = Bl8[((s + 1) * 8 + t0) * 64 + lane];
            nl1 = Bl8[((s + 1) * 8 + t0 + 1) * 64 + lane];
        }
        int kf = s * 32 + g * 8;
        bf16x8 a_h[2], a_l[2];
        #pragma unroll
        for (int m = 0; m < 2; ++m) {
            a_h[m] = *(const bf16x8*)&Ah[m * 16 + rowid][kf];
            a_l[m] = *(const bf16x8*)&Al[m * 16 + rowid][kf];
        }
        #pragma unroll
        for (int m = 0; m < 2; ++m) {
            acc[m][0] = __builtin_amdgcn_mfma_f32_16x16x32_bf16(a_h[m], bh0, acc[m][0], 0, 0, 0);
            acc[m][1] = __builtin_amdgcn_mfma_f32_16x16x32_bf16(a_h[m], bh1, acc[m][1], 0, 0, 0);
            acc[m][0] = __builtin_amdgcn_mfma_f32_16x16x32_bf16(a_l[m], bh0, acc[m][0], 0, 0, 0);
            acc[m][1] = __builtin_amdgcn_mfma_f32_16x16x32_bf16(a_l[m], bh1, acc[m][1], 0, 0, 0);
            acc[m][0] = __builtin_amdgcn_mfma_f32_16x16x32_bf16(a_h[m], bl0, acc[m][0], 0, 0, 0);
            acc[m][1] = __builtin_amdgcn_mfma_f32_16x16x32_bf16(a_h[m], bl1, acc[m][1], 0, 0, 0);
        }
        bh0 = nh0; bh1 = nh1; bl0 = nl0; bl1 = nl1;
    }

    int n0 = w * 32 + rowid;
    int n1 = n0 + 16;
    float b_0 = bias[n0], b_1 = bias[n1];
    unsigned short* OhU = (unsigned short*)Oh;
    unsigned short* OlU = (unsigned short*)Ol;
    #pragma unroll
    for (int m = 0; m < 2; ++m) {
        int node = node0 + m * 16 + g * 4;
        #pragma unroll
        for (int r = 0; r < 4; ++r) {
            if (node + r < n_nodes) {
                float v0 = fmaxf(acc[m][0][r] + b_0, 0.f);
                float v1 = fmaxf(acc[m][1][r] + b_1, 0.f);
                short h0 = f2bf(v0), l0 = f2bf(v0 - bf2f(h0));
                short h1 = f2bf(v1), l1 = f2bf(v1 - bf2f(h1));
                OhU[(node + r) * 128 + n0] = (unsigned short)h0;
                OlU[(node + r) * 128 + n0] = (unsigned short)l0;
                OhU[(node + r) * 128 + n1] = (unsigned short)h1;
                OlU[(node + r) * 128 + n1] = (unsigned short)l1;
            }
        }
    }
}

// ---------------- UV GEMM: [U|V] = h2 @ [Wm1_s; Wm1_d]^T (K=128) -----------
__global__ __launch_bounds__(256, 4) void k_guv(
    const short* __restrict__ H2h, const short* __restrict__ H2l,
    const short* __restrict__ Bh, const short* __restrict__ Bl,
    float* __restrict__ U, float* __restrict__ V, int n_nodes) {
    __shared__ __align__(16) short Ah[32][136];
    __shared__ __align__(16) short Al[32][136];
    int tid = threadIdx.x;
    int node0 = blockIdx.x * 32;
    const s16x8* Hh8 = (const s16x8*)H2h;
    const s16x8* Hl8 = (const s16x8*)H2l;
    for (int i = tid; i < 32 * 16; i += 256) {
        int row = i >> 4, grp = i & 15;
        int node = node0 + row;
        s16x8 vh = (s16x8)0, vl = (s16x8)0;
        if (node < n_nodes) {
            vh = Hh8[node * 16 + grp];
            vl = Hl8[node * 16 + grp];
        }
        *(s16x8*)&Ah[row][grp * 8] = vh;
        *(s16x8*)&Al[row][grp * 8] = vl;
    }
    __syncthreads();

    int lane = tid & 63;
    int w = tid >> 6;
    int rowid = lane & 15;
    int g = lane >> 4;
    int t0 = w * 4;

    f32x4 acc[2][4];
    #pragma unroll
    for (int m = 0; m < 2; ++m)
        #pragma unroll
        for (int q = 0; q < 4; ++q) acc[m][q] = (f32x4)0.f;

    const bf16x8* Bh8 = (const bf16x8*)Bh;
    const bf16x8* Bl8 = (const bf16x8*)Bl;

    #pragma unroll
    for (int s = 0; s < 4; ++s) {
        bf16x8 bh[4], bl[4];
        #pragma unroll
        for (int q = 0; q < 4; ++q) {
            bh[q] = Bh8[(s * 16 + t0 + q) * 64 + lane];
            bl[q] = Bl8[(s * 16 + t0 + q) * 64 + lane];
        }
        int kf = s * 32 + g * 8;
        bf16x8 a_h[2], a_l[2];
        #pragma unroll
        for (int m = 0; m < 2; ++m) {
            a_h[m] = *(const bf16x8*)&Ah[m * 16 + rowid][kf];
            a_l[m] = *(const bf16x8*)&Al[m * 16 + rowid][kf];
        }
        #pragma unroll
        for (int m = 0; m < 2; ++m) {
            #pragma unroll
            for (int q = 0; q < 4; ++q) {
                acc[m][q] = __builtin_amdgcn_mfma_f32_16x16x32_bf16(a_h[m], bh[q], acc[m][q], 0, 0, 0);
                acc[m][q] = __builtin_amdgcn_mfma_f32_16x16x32_bf16(a_l[m], bh[q], acc[m][q], 0, 0, 0);
                acc[m][q] = __builtin_amdgcn_mfma_f32_16x16x32_bf16(a_h[m], bl[q], acc[m][q], 0, 0, 0);
            }
        }
    }

    float* dstbase = (w < 2) ? U : V;
    int cb = (w & 1) * 64 + rowid;
    #pragma unroll
    for (int m = 0; m < 2; ++m) {
        int node = node0 + m * 16 + g * 4;
        #pragma unroll
        for (int q = 0; q < 4; ++q) {
            int col = cb + q * 16;
            #pragma unroll
            for (int r = 0; r < 4; ++r) {
                if (node + r < n_nodes)
                    dstbase[(node + r) * 128 + col] = acc[m][q][r];
            }
        }
    }
}

// ---------------- streaming edge kernel (LDS attr-weights, 1 edge/wave) -----
// out = wm2 . relu(U[s] + V[d] + Wa@attr + bm1) + bm2
// Wa staged in LDS k-major [16][128]; lane reads float2 at 8*lane (contiguous,
// conflict-free). Bare launch_bounds -> compiler targets 8 waves/SIMD.
__global__ __launch_bounds__(256) void k_edge(
    const float* __restrict__ U, const float* __restrict__ V,
    const int* __restrict__ ps, const int* __restrict__ pd,
    const float* __restrict__ attr, const float* __restrict__ Wm1,
    const float* __restrict__ bm1, const float* __restrict__ wm2,
    const float* __restrict__ bm2, float* __restrict__ outp, int n_edges) {
    __shared__ float waLds[16][128];   // [k][j]
    int tid = threadIdx.x;
    for (int i = tid; i < 16 * 128; i += 256) {
        int k = i >> 7, j = i & 127;
        waLds[k][j] = Wm1[j * 272 + 256 + k];
    }
    __syncthreads();

    int lane = tid & 63;
    int wid = (blockIdx.x * 256 + tid) >> 6;
    int nw = (gridDim.x * 256) >> 6;

    int j0 = 2 * lane;
    float bb0 = bm1[j0], bb1 = bm1[j0 + 1];
    float wm0 = wm2[j0], wmv1 = wm2[j0 + 1];
    float bm2v = bm2[0];

    const float2* U2 = (const float2*)U;
    const float2* V2 = (const float2*)V;
    const float4* at4 = (const float4*)attr;

    for (int e = wid; e < n_edges; e += nw) {
        int s = ps[e];
        int d = pd[e];
        float2 u = U2[(size_t)s * 64 + lane];
        float2 v = V2[(size_t)d * 64 + lane];
        float4 a0 = at4[(size_t)e * 4 + 0];
        float4 a1 = at4[(size_t)e * 4 + 1];
        float4 a2 = at4[(size_t)e * 4 + 2];
        float4 a3 = at4[(size_t)e * 4 + 3];
        float av[16] = {a0.x, a0.y, a0.z, a0.w, a1.x, a1.y, a1.z, a1.w,
                        a2.x, a2.y, a2.z, a2.w, a3.x, a3.y, a3.z, a3.w};
        float t0 = 0.f, t1 = 0.f;
        #pragma unroll
        for (int k = 0; k < 16; ++k) {
            float2 wv = *(const float2*)&waLds[k][j0];
            t0 += wv.x * av[k];
            t1 += wv.y * av[k];
        }
        float p = fmaxf(u.x + v.x + t0 + bb0, 0.f) * wm0
                + fmaxf(u.y + v.y + t1 + bb1, 0.f) * wmv1;
        p += __shfl_xor(p, 32, 64);
        p += __shfl_xor(p, 16, 64);
        p += __shfl_xor(p, 8, 64);
        p += __shfl_xor(p, 4, 64);
        p += __shfl_xor(p, 2, 64);
        p += __shfl_xor(p, 1, 64);
        if (lane == 0) outp[e] = p + bm2v;
    }
}

extern "C" void kernel_launch(void* const* d_in, const int* in_sizes, int n_in,
                              void* d_out, int out_size, void* d_ws, size_t ws_size,
                              hipStream_t stream) {
    const float* x     = (const float*)d_in[0];
    const int*   mp    = (const int*)d_in[1];
    const int*   pe    = (const int*)d_in[2];
    const float* attr  = (const float*)d_in[3];
    const float* W1_l  = (const float*)d_in[4];
    const float* b1    = (const float*)d_in[5];
    const float* W1_r  = (const float*)d_in[6];
    const float* W2_l  = (const float*)d_in[7];
    const float* b2    = (const float*)d_in[8];
    const float* W2_r  = (const float*)d_in[9];
    const float* Wm1   = (const float*)d_in[10];
    const float* bm1   = (const float*)d_in[11];
    const float* Wm2   = (const float*)d_in[12];
    const float* bm2   = (const float*)d_in[13];
    float* out = (float*)d_out;

    const int n_nodes = in_sizes[0] / HIDDEN;   // 50000
    const int n_mp    = in_sizes[1] / 2;        // 800000
    const int n_pred  = in_sizes[2] / 2;        // 400000

    const int* mp_src = mp;
    const int* mp_dst = mp + n_mp;
    const int* p_src  = pe;
    const int* p_dst  = pe + n_pred;

    char* ws = (char*)d_ws;
    size_t off = 0;
    auto alloc = [&](size_t bytes) -> void* {
        void* p = ws + off;
        off += (bytes + 255) & ~(size_t)255;
        return p;
    };
    short* Wc1h = (short*)alloc(8 * 8 * 64 * 8 * sizeof(short));
    short* Wc1l = (short*)alloc(8 * 8 * 64 * 8 * sizeof(short));
    short* Wc2h = (short*)alloc(8 * 8 * 64 * 8 * sizeof(short));
    short* Wc2l = (short*)alloc(8 * 8 * 64 * 8 * sizeof(short));
    short* Buvh = (short*)alloc(4 * 16 * 64 * 8 * sizeof(short));
    short* Buvl = (short*)alloc(4 * 16 * 64 * 8 * sizeof(short));
    int*   deg    = (int*)alloc((size_t)n_nodes * sizeof(int));
    int*   rowst  = (int*)alloc(((size_t)n_nodes + 1) * sizeof(int));
    int*   cursor = (int*)alloc((size_t)n_nodes * sizeof(int));
    int*   part   = (int*)alloc(64 * sizeof(int));
    int*   csr    = (int*)alloc((size_t)n_mp * sizeof(int));
    short* Xh  = (short*)alloc((size_t)n_nodes * HIDDEN * sizeof(short));
    short* Xl  = (short*)alloc((size_t)n_nodes * HIDDEN * sizeof(short));
    short* Mh  = (short*)alloc((size_t)n_nodes * HIDDEN * sizeof(short));
    short* Ml  = (short*)alloc((size_t)n_nodes * HIDDEN * sizeof(short));
    short* H1h = (short*)alloc((size_t)n_nodes * HIDDEN * sizeof(short));
    short* H1l = (short*)alloc((size_t)n_nodes * HIDDEN * sizeof(short));
    short* H2h = (short*)alloc((size_t)n_nodes * HIDDEN * sizeof(short));
    short* H2l = (short*)alloc((size_t)n_nodes * HIDDEN * sizeof(short));
    float* Ubuf = (float*)alloc((size_t)n_nodes * HIDDEN * sizeof(float));
    float* Vbuf = (float*)alloc((size_t)n_nodes * HIDDEN * sizeof(float));
    (void)ws_size; (void)n_in; (void)out_size;

    const int P = (n_nodes + 1023) / 1024;        // 49 scan blocks (<=64)
    const int degb = (n_nodes + 255) / 256;       // deg-zero blocks
    const int nsplit4 = n_nodes * 32;             // float4 groups in x
    const int splitb = (nsplit4 + 255) / 256;

    // fused prep: packs + deg zero + x split
    k_prep<<<48 + degb + splitb, 256, 0, stream>>>(x, W1_l, W1_r, W2_l, W2_r, Wm1,
                                                   Wc1h, Wc1l, Wc2h, Wc2l, Buvh, Buvl,
                                                   Xh, Xl, deg, n_nodes, degb, nsplit4);

    // CSR build
    k_deg<<<(n_mp + 255) / 256, 256, 0, stream>>>(mp_dst, deg, n_mp);
    k_scan_blk<<<P, 1024, 0, stream>>>(deg, rowst, part, n_nodes);
    k_scan_top<<<1, 64, 0, stream>>>(part, rowst, P, n_nodes);
    k_scan_add<<<P, 1024, 0, stream>>>(rowst, cursor, part, n_nodes);
    k_fill<<<(n_mp + 255) / 256, 256, 0, stream>>>(mp_src, mp_dst, cursor, csr, n_mp);

    // conv1
    k_agg_f32<<<(n_nodes + 3) / 4, 256, 0, stream>>>(x, rowst, csr, Mh, Ml, n_nodes);
    k_convm<<<(n_nodes + 31) / 32, 256, 0, stream>>>(Mh, Ml, Xh, Xl, Wc1h, Wc1l, b1,
                                                     H1h, H1l, n_nodes);
    // conv2
    k_agg_sp<<<(n_nodes + 3) / 4, 256, 0, stream>>>(H1h, H1l, rowst, csr, Mh, Ml, n_nodes);
    k_convm<<<(n_nodes + 31) / 32, 256, 0, stream>>>(Mh, Ml, H1h, H1l, Wc2h, Wc2l, b2,
                                                     H2h, H2l, n_nodes);

    // UV GEMM + streaming edge MLP
    k_guv<<<(n_nodes + 31) / 32, 256, 0, stream>>>(H2h, H2l, Buvh, Buvl, Ubuf, Vbuf, n_nodes);
    k_edge<<<2048, 256, 0, stream>>>(Ubuf, Vbuf, p_src, p_dst, attr, Wm1,
                                     bm1, Wm2, bm2, out, n_pred);
}

// Round 10
// 481.109 us; speedup vs baseline: 1.2631x; 1.1474x over previous
//
#include <hip/hip_runtime.h>
#include <hip/hip_bf16.h>

#define HIDDEN 128

typedef __attribute__((ext_vector_type(8))) short s16x8;
typedef __attribute__((ext_vector_type(4))) short s16x4;
typedef __attribute__((ext_vector_type(4))) float f32x4;
typedef __attribute__((ext_vector_type(8))) __bf16 bf16x8;

__device__ __forceinline__ short f2bf(float x) {
    unsigned u = __float_as_uint(x);
    unsigned r = (u + 0x7fffu + ((u >> 16) & 1u)) >> 16;   // round-to-nearest-even
    return (short)r;
}
__device__ __forceinline__ float bf2f(short s) {
    return __uint_as_float(((unsigned)(unsigned short)s) << 16);
}

// ---------------- fused prep: weight packing + x split + deg zero ----------
__device__ __forceinline__ void pack_conv_body(const float* __restrict__ Wl,
                                               const float* __restrict__ Wr,
                                               short* __restrict__ Bh,
                                               short* __restrict__ Bl, int idx) {
    int l = idx & 63;
    int t = (idx >> 6) & 7;
    int s = idx >> 9;
    int n = t * 16 + (l & 15);
    int kbase = s * 32 + (l >> 4) * 8;
    s16x8 h, lo;
    #pragma unroll
    for (int j = 0; j < 8; ++j) {
        int k = kbase + j;
        float v = (k < 128) ? Wl[n * 128 + k] : Wr[n * 128 + (k - 128)];
        short hs = f2bf(v);
        h[j] = hs;
        lo[j] = f2bf(v - bf2f(hs));
    }
    ((s16x8*)Bh)[idx] = h;
    ((s16x8*)Bl)[idx] = lo;
}

__device__ __forceinline__ void pack_uv_body(const float* __restrict__ Wm1,
                                             short* __restrict__ Bh,
                                             short* __restrict__ Bl, int idx) {
    int l = idx & 63;
    int t = (idx >> 6) & 15;
    int s = idx >> 10;
    int np = t * 16 + (l & 15);
    int kbase = s * 32 + (l >> 4) * 8;
    s16x8 h, lo;
    #pragma unroll
    for (int j = 0; j < 8; ++j) {
        int k = kbase + j;
        float v = (np < 128) ? Wm1[np * 272 + k] : Wm1[(np - 128) * 272 + 128 + k];
        short hs = f2bf(v);
        h[j] = hs;
        lo[j] = f2bf(v - bf2f(hs));
    }
    ((s16x8*)Bh)[idx] = h;
    ((s16x8*)Bl)[idx] = lo;
}

__global__ void k_prep(const float* __restrict__ x,
                       const float* __restrict__ W1_l, const float* __restrict__ W1_r,
                       const float* __restrict__ W2_l, const float* __restrict__ W2_r,
                       const float* __restrict__ Wm1,
                       short* __restrict__ Wc1h, short* __restrict__ Wc1l,
                       short* __restrict__ Wc2h, short* __restrict__ Wc2l,
                       short* __restrict__ Buvh, short* __restrict__ Buvl,
                       short* __restrict__ Xh, short* __restrict__ Xl,
                       int* __restrict__ deg, int n_nodes, int degb, int nsplit4) {
    int b = blockIdx.x;
    int tid = threadIdx.x;
    if (b < 16) {
        pack_conv_body(W1_l, W1_r, Wc1h, Wc1l, b * 256 + tid);
    } else if (b < 32) {
        pack_conv_body(W2_l, W2_r, Wc2h, Wc2l, (b - 16) * 256 + tid);
    } else if (b < 48) {
        pack_uv_body(Wm1, Buvh, Buvl, (b - 32) * 256 + tid);
    } else if (b < 48 + degb) {
        int i = (b - 48) * 256 + tid;
        if (i < n_nodes) deg[i] = 0;
    } else {
        int i = (b - 48 - degb) * 256 + tid;
        if (i < nsplit4) {
            float4 v = ((const float4*)x)[i];
            s16x4 h, l;
            h[0] = f2bf(v.x); l[0] = f2bf(v.x - bf2f(h[0]));
            h[1] = f2bf(v.y); l[1] = f2bf(v.y - bf2f(h[1]));
            h[2] = f2bf(v.z); l[2] = f2bf(v.z - bf2f(h[2]));
            h[3] = f2bf(v.w); l[3] = f2bf(v.w - bf2f(h[3]));
            ((s16x4*)Xh)[i] = h;
            ((s16x4*)Xl)[i] = l;
        }
    }
}

// ---------------- CSR construction ----------------
__global__ void k_deg(const int* __restrict__ dst, int* __restrict__ deg, int n_edges) {
    for (int e = blockIdx.x * blockDim.x + threadIdx.x; e < n_edges; e += gridDim.x * blockDim.x)
        atomicAdd(&deg[dst[e]], 1);
}

__global__ __launch_bounds__(1024) void k_scan_blk(const int* __restrict__ deg,
                                                   int* __restrict__ row_start,
                                                   int* __restrict__ part, int n) {
    __shared__ int wsum[16];
    int tid = threadIdx.x;
    int lane = tid & 63;
    int w = tid >> 6;
    int i = blockIdx.x * 1024 + tid;
    int v = (i < n) ? deg[i] : 0;
    int s = v;
    #pragma unroll
    for (int off = 1; off < 64; off <<= 1) {
        int t = __shfl_up(s, off, 64);
        if (lane >= off) s += t;
    }
    if (lane == 63) wsum[w] = s;
    __syncthreads();
    if (w == 0) {
        int ws = (lane < 16) ? wsum[lane] : 0;
        #pragma unroll
        for (int off = 1; off < 16; off <<= 1) {
            int t = __shfl_up(ws, off, 64);
            if (lane >= off) ws += t;
        }
        if (lane < 16) wsum[lane] = ws;
    }
    __syncthreads();
    int incl = s + ((w > 0) ? wsum[w - 1] : 0);
    if (i < n) row_start[i] = incl - v;
    if (tid == 1023) part[blockIdx.x] = incl;
}

__global__ void k_scan_top(int* __restrict__ part, int* __restrict__ row_start,
                           int P, int n) {
    int lane = threadIdx.x;
    int v = (lane < P) ? part[lane] : 0;
    int s = v;
    #pragma unroll
    for (int off = 1; off < 64; off <<= 1) {
        int t = __shfl_up(s, off, 64);
        if (lane >= off) s += t;
    }
    if (lane < P) part[lane] = s - v;
    if (lane == P - 1) row_start[n] = s;
}

__global__ __launch_bounds__(1024) void k_scan_add(int* __restrict__ row_start,
                                                   int* __restrict__ cursor,
                                                   const int* __restrict__ part, int n) {
    int i = blockIdx.x * 1024 + threadIdx.x;
    if (i < n) {
        int r = row_start[i] + part[blockIdx.x];
        row_start[i] = r;
        cursor[i] = r;
    }
}

__global__ void k_fill(const int* __restrict__ src, const int* __restrict__ dst,
                       int* __restrict__ cursor, int* __restrict__ csr, int n_edges) {
    for (int e = blockIdx.x * blockDim.x + threadIdx.x; e < n_edges; e += gridDim.x * blockDim.x) {
        int d = dst[e];
        int p = atomicAdd(&cursor[d], 1);
        csr[p] = src[e];
    }
}

// ---------------- mean aggregation (fp32 input) -> split hi/lo tables -------
// one 64-lane wave per node; lane owns features 2*lane, 2*lane+1; 4x unroll
__global__ __launch_bounds__(256) void k_agg_f32(const float* __restrict__ feat,
                                                 const int* __restrict__ row_start,
                                                 const int* __restrict__ csr,
                                                 short* __restrict__ Mh,
                                                 short* __restrict__ Ml, int n_nodes) {
    int wave = (blockIdx.x * 256 + threadIdx.x) >> 6;
    if (wave >= n_nodes) return;
    int lane = threadIdx.x & 63;
    int s = row_start[wave], e = row_start[wave + 1];
    const float2* f2p = (const float2*)feat;
    float ax = 0.f, ay = 0.f;
    int j = s;
    for (; j + 3 < e; j += 4) {
        int nb0 = csr[j];
        int nb1 = csr[j + 1];
        int nb2 = csr[j + 2];
        int nb3 = csr[j + 3];
        float2 v0 = f2p[(size_t)nb0 * 64 + lane];
        float2 v1 = f2p[(size_t)nb1 * 64 + lane];
        float2 v2 = f2p[(size_t)nb2 * 64 + lane];
        float2 v3 = f2p[(size_t)nb3 * 64 + lane];
        ax += (v0.x + v1.x) + (v2.x + v3.x);
        ay += (v0.y + v1.y) + (v2.y + v3.y);
    }
    for (; j < e; ++j) {
        int nb = csr[j];
        float2 v = f2p[(size_t)nb * 64 + lane];
        ax += v.x; ay += v.y;
    }
    float inv = (e > s) ? 1.0f / (float)(e - s) : 0.0f;
    float m0 = ax * inv, m1 = ay * inv;
    short h0 = f2bf(m0), l0 = f2bf(m0 - bf2f(h0));
    short h1 = f2bf(m1), l1 = f2bf(m1 - bf2f(h1));
    ((ushort2*)Mh)[wave * 64 + lane] = make_ushort2((unsigned short)h0, (unsigned short)h1);
    ((ushort2*)Ml)[wave * 64 + lane] = make_ushort2((unsigned short)l0, (unsigned short)l1);
}

// ---------------- mean aggregation from split hi/lo tables (lane-split) -----
// lanes 0..31 read the HI table row, lanes 32..63 the LO row; 4x unroll
__global__ __launch_bounds__(256) void k_agg_sp(const short* __restrict__ Fh,
                                                const short* __restrict__ Fl,
                                                const int* __restrict__ row_start,
                                                const int* __restrict__ csr,
                                                short* __restrict__ Mh,
                                                short* __restrict__ Ml, int n_nodes) {
    int wave = (blockIdx.x * 256 + threadIdx.x) >> 6;
    if (wave >= n_nodes) return;
    int lane = threadIdx.x & 63;
    int half = lane >> 5;
    int l32 = lane & 31;
    const s16x4* base = (const s16x4*)(half ? Fl : Fh);
    int s = row_start[wave], e = row_start[wave + 1];
    float a0 = 0.f, a1 = 0.f, a2 = 0.f, a3 = 0.f;
    int j = s;
    for (; j + 3 < e; j += 4) {
        int nb0 = csr[j];
        int nb1 = csr[j + 1];
        int nb2 = csr[j + 2];
        int nb3 = csr[j + 3];
        s16x4 q0 = base[(size_t)nb0 * 32 + l32];
        s16x4 q1 = base[(size_t)nb1 * 32 + l32];
        s16x4 q2 = base[(size_t)nb2 * 32 + l32];
        s16x4 q3 = base[(size_t)nb3 * 32 + l32];
        a0 += (bf2f(q0[0]) + bf2f(q1[0])) + (bf2f(q2[0]) + bf2f(q3[0]));
        a1 += (bf2f(q0[1]) + bf2f(q1[1])) + (bf2f(q2[1]) + bf2f(q3[1]));
        a2 += (bf2f(q0[2]) + bf2f(q1[2])) + (bf2f(q2[2]) + bf2f(q3[2]));
        a3 += (bf2f(q0[3]) + bf2f(q1[3])) + (bf2f(q2[3]) + bf2f(q3[3]));
    }
    for (; j < e; ++j) {
        int nb = csr[j];
        s16x4 q = base[(size_t)nb * 32 + l32];
        a0 += bf2f(q[0]); a1 += bf2f(q[1]); a2 += bf2f(q[2]); a3 += bf2f(q[3]);
    }
    a0 += __shfl_xor(a0, 32, 64);
    a1 += __shfl_xor(a1, 32, 64);
    a2 += __shfl_xor(a2, 32, 64);
    a3 += __shfl_xor(a3, 32, 64);
    float inv = (e > s) ? 1.0f / (float)(e - s) : 0.0f;
    float m0 = a0 * inv, m1 = a1 * inv, m2 = a2 * inv, m3 = a3 * inv;
    short h0 = f2bf(m0), h1 = f2bf(m1), h2 = f2bf(m2), h3 = f2bf(m3);
    s16x4 o;
    if (half == 0) {
        o[0] = h0; o[1] = h1; o[2] = h2; o[3] = h3;
    } else {
        o[0] = f2bf(m0 - bf2f(h0));
        o[1] = f2bf(m1 - bf2f(h1));
        o[2] = f2bf(m2 - bf2f(h2));
        o[3] = f2bf(m3 - bf2f(h3));
    }
    ((s16x4*)(half ? Ml : Mh))[(size_t)wave * 32 + l32] = o;
}

// ---------------- SAGE conv via split-bf16 MFMA ----------------
__global__ __launch_bounds__(256, 4) void k_convm(
    const short* __restrict__ Mh, const short* __restrict__ Ml,
    const short* __restrict__ Rh, const short* __restrict__ Rl,
    const short* __restrict__ Bh, const short* __restrict__ Bl,
    const float* __restrict__ bias, short* __restrict__ Oh, short* __restrict__ Ol,
    int n_nodes) {
    __shared__ __align__(16) short Ah[32][264];
    __shared__ __align__(16) short Al[32][264];
    int tid = threadIdx.x;
    int node0 = blockIdx.x * 32;
    const s16x8* Mh8 = (const s16x8*)Mh;
    const s16x8* Ml8 = (const s16x8*)Ml;
    const s16x8* Rh8 = (const s16x8*)Rh;
    const s16x8* Rl8 = (const s16x8*)Rl;
    for (int i = tid; i < 32 * 32; i += 256) {
        int row = i >> 5, grp = i & 31;
        int node = node0 + row;
        s16x8 vh = (s16x8)0, vl = (s16x8)0;
        if (node < n_nodes) {
            vh = (grp < 16) ? Mh8[node * 16 + grp] : Rh8[node * 16 + (grp - 16)];
            vl = (grp < 16) ? Ml8[node * 16 + grp] : Rl8[node * 16 + (grp - 16)];
        }
        *(s16x8*)&Ah[row][grp * 8] = vh;
        *(s16x8*)&Al[row][grp * 8] = vl;
    }
    __syncthreads();

    int lane = tid & 63;
    int w = tid >> 6;
    int rowid = lane & 15;
    int g = lane >> 4;
    int t0 = w * 2;

    f32x4 acc[2][2];
    acc[0][0] = (f32x4)0.f; acc[0][1] = (f32x4)0.f;
    acc[1][0] = (f32x4)0.f; acc[1][1] = (f32x4)0.f;

    const bf16x8* Bh8 = (const bf16x8*)Bh;
    const bf16x8* Bl8 = (const bf16x8*)Bl;
    bf16x8 bh0 = Bh8[t0 * 64 + lane];
    bf16x8 bh1 = Bh8[(t0 + 1) * 64 + lane];
    bf16x8 bl0 = Bl8[t0 * 64 + lane];
    bf16x8 bl1 = Bl8[(t0 + 1) * 64 + lane];

    #pragma unroll
    for (int s = 0; s < 8; ++s) {
        bf16x8 nh0 = bh0, nh1 = bh1, nl0 = bl0, nl1 = bl1;
        if (s < 7) {
            nh0 = Bh8[((s + 1) * 8 + t0) * 64 + lane];
            nh1 = Bh8[((s + 1) * 8 + t0 + 1) * 64 + lane];
            nl0 = Bl8[((s + 1) * 8 + t0) * 64 + lane];
            nl1 = Bl8[((s + 1) * 8 + t0 + 1) * 64 + lane];
        }
        int kf = s * 32 + g * 8;
        bf16x8 a_h[2], a_l[2];
        #pragma unroll
        for (int m = 0; m < 2; ++m) {
            a_h[m] = *(const bf16x8*)&Ah[m * 16 + rowid][kf];
            a_l[m] = *(const bf16x8*)&Al[m * 16 + rowid][kf];
        }
        #pragma unroll
        for (int m = 0; m < 2; ++m) {
            acc[m][0] = __builtin_amdgcn_mfma_f32_16x16x32_bf16(a_h[m], bh0, acc[m][0], 0, 0, 0);
            acc[m][1] = __builtin_amdgcn_mfma_f32_16x16x32_bf16(a_h[m], bh1, acc[m][1], 0, 0, 0);
            acc[m][0] = __builtin_amdgcn_mfma_f32_16x16x32_bf16(a_l[m], bh0, acc[m][0], 0, 0, 0);
            acc[m][1] = __builtin_amdgcn_mfma_f32_16x16x32_bf16(a_l[m], bh1, acc[m][1], 0, 0, 0);
            acc[m][0] = __builtin_amdgcn_mfma_f32_16x16x32_bf16(a_h[m], bl0, acc[m][0], 0, 0, 0);
            acc[m][1] = __builtin_amdgcn_mfma_f32_16x16x32_bf16(a_h[m], bl1, acc[m][1], 0, 0, 0);
        }
        bh0 = nh0; bh1 = nh1; bl0 = nl0; bl1 = nl1;
    }

    int n0 = w * 32 + rowid;
    int n1 = n0 + 16;
    float b_0 = bias[n0], b_1 = bias[n1];
    unsigned short* OhU = (unsigned short*)Oh;
    unsigned short* OlU = (unsigned short*)Ol;
    #pragma unroll
    for (int m = 0; m < 2; ++m) {
        int node = node0 + m * 16 + g * 4;
        #pragma unroll
        for (int r = 0; r < 4; ++r) {
            if (node + r < n_nodes) {
                float v0 = fmaxf(acc[m][0][r] + b_0, 0.f);
                float v1 = fmaxf(acc[m][1][r] + b_1, 0.f);
                short h0 = f2bf(v0), l0 = f2bf(v0 - bf2f(h0));
                short h1 = f2bf(v1), l1 = f2bf(v1 - bf2f(h1));
                OhU[(node + r) * 128 + n0] = (unsigned short)h0;
                OlU[(node + r) * 128 + n0] = (unsigned short)l0;
                OhU[(node + r) * 128 + n1] = (unsigned short)h1;
                OlU[(node + r) * 128 + n1] = (unsigned short)l1;
            }
        }
    }
}

// ---------------- UV GEMM: [U|V] = h2 @ [Wm1_s; Wm1_d]^T (K=128) -----------
__global__ __launch_bounds__(256, 4) void k_guv(
    const short* __restrict__ H2h, const short* __restrict__ H2l,
    const short* __restrict__ Bh, const short* __restrict__ Bl,
    float* __restrict__ U, float* __restrict__ V, int n_nodes) {
    __shared__ __align__(16) short Ah[32][136];
    __shared__ __align__(16) short Al[32][136];
    int tid = threadIdx.x;
    int node0 = blockIdx.x * 32;
    const s16x8* Hh8 = (const s16x8*)H2h;
    const s16x8* Hl8 = (const s16x8*)H2l;
    for (int i = tid; i < 32 * 16; i += 256) {
        int row = i >> 4, grp = i & 15;
        int node = node0 + row;
        s16x8 vh = (s16x8)0, vl = (s16x8)0;
        if (node < n_nodes) {
            vh = Hh8[node * 16 + grp];
            vl = Hl8[node * 16 + grp];
        }
        *(s16x8*)&Ah[row][grp * 8] = vh;
        *(s16x8*)&Al[row][grp * 8] = vl;
    }
    __syncthreads();

    int lane = tid & 63;
    int w = tid >> 6;
    int rowid = lane & 15;
    int g = lane >> 4;
    int t0 = w * 4;

    f32x4 acc[2][4];
    #pragma unroll
    for (int m = 0; m < 2; ++m)
        #pragma unroll
        for (int q = 0; q < 4; ++q) acc[m][q] = (f32x4)0.f;

    const bf16x8* Bh8 = (const bf16x8*)Bh;
    const bf16x8* Bl8 = (const bf16x8*)Bl;

    #pragma unroll
    for (int s = 0; s < 4; ++s) {
        bf16x8 bh[4], bl[4];
        #pragma unroll
        for (int q = 0; q < 4; ++q) {
            bh[q] = Bh8[(s * 16 + t0 + q) * 64 + lane];
            bl[q] = Bl8[(s * 16 + t0 + q) * 64 + lane];
        }
        int kf = s * 32 + g * 8;
        bf16x8 a_h[2], a_l[2];
        #pragma unroll
        for (int m = 0; m < 2; ++m) {
            a_h[m] = *(const bf16x8*)&Ah[m * 16 + rowid][kf];
            a_l[m] = *(const bf16x8*)&Al[m * 16 + rowid][kf];
        }
        #pragma unroll
        for (int m = 0; m < 2; ++m) {
            #pragma unroll
            for (int q = 0; q < 4; ++q) {
                acc[m][q] = __builtin_amdgcn_mfma_f32_16x16x32_bf16(a_h[m], bh[q], acc[m][q], 0, 0, 0);
                acc[m][q] = __builtin_amdgcn_mfma_f32_16x16x32_bf16(a_l[m], bh[q], acc[m][q], 0, 0, 0);
                acc[m][q] = __builtin_amdgcn_mfma_f32_16x16x32_bf16(a_h[m], bl[q], acc[m][q], 0, 0, 0);
            }
        }
    }

    float* dstbase = (w < 2) ? U : V;
    int cb = (w & 1) * 64 + rowid;
    #pragma unroll
    for (int m = 0; m < 2; ++m) {
        int node = node0 + m * 16 + g * 4;
        #pragma unroll
        for (int q = 0; q < 4; ++q) {
            int col = cb + q * 16;
            #pragma unroll
            for (int r = 0; r < 4; ++r) {
                if (node + r < n_nodes)
                    dstbase[(node + r) * 128 + col] = acc[m][q][r];
            }
        }
    }
}

// ---------------- streaming edge kernel (round-6 proven form) ----------------
// one wave per edge (grid-stride): out = wm2 . relu(U[s] + V[d] + Wa@attr + bm1) + bm2
__global__ __launch_bounds__(256) void k_edge(
    const float* __restrict__ U, const float* __restrict__ V,
    const int* __restrict__ ps, const int* __restrict__ pd,
    const float* __restrict__ attr, const float* __restrict__ Wm1,
    const float* __restrict__ bm1, const float* __restrict__ wm2,
    const float* __restrict__ bm2, float* __restrict__ outp, int n_edges) {
    int lane = threadIdx.x & 63;
    int wid = (blockIdx.x * 256 + threadIdx.x) >> 6;
    int nw = (gridDim.x * 256) >> 6;

    int j0 = 2 * lane;
    // hoist attr-columns of Wm1 (Wa[j][k] = Wm1[j*272 + 256 + k]) for j0, j0+1
    float wa0[16], wa1[16];
    #pragma unroll
    for (int k4 = 0; k4 < 4; ++k4) {
        float4 t = *(const float4*)&Wm1[j0 * 272 + 256 + k4 * 4];
        wa0[k4 * 4 + 0] = t.x; wa0[k4 * 4 + 1] = t.y; wa0[k4 * 4 + 2] = t.z; wa0[k4 * 4 + 3] = t.w;
        float4 u = *(const float4*)&Wm1[(j0 + 1) * 272 + 256 + k4 * 4];
        wa1[k4 * 4 + 0] = u.x; wa1[k4 * 4 + 1] = u.y; wa1[k4 * 4 + 2] = u.z; wa1[k4 * 4 + 3] = u.w;
    }
    float bb0 = bm1[j0], bb1 = bm1[j0 + 1];
    float wm0 = wm2[j0], wm1v = wm2[j0 + 1];
    float bm2v = bm2[0];

    const float2* U2 = (const float2*)U;
    const float2* V2 = (const float2*)V;
    const float4* at4 = (const float4*)attr;

    for (int e = wid; e < n_edges; e += nw) {
        int s = ps[e];
        int d = pd[e];
        float2 u = U2[s * 64 + lane];
        float2 v = V2[d * 64 + lane];
        float4 a0 = at4[e * 4 + 0];
        float4 a1 = at4[e * 4 + 1];
        float4 a2 = at4[e * 4 + 2];
        float4 a3 = at4[e * 4 + 3];
        float av[16] = {a0.x, a0.y, a0.z, a0.w, a1.x, a1.y, a1.z, a1.w,
                        a2.x, a2.y, a2.z, a2.w, a3.x, a3.y, a3.z, a3.w};
        float t0 = 0.f, t1 = 0.f;
        #pragma unroll
        for (int k = 0; k < 16; ++k) {
            t0 += wa0[k] * av[k];
            t1 += wa1[k] * av[k];
        }
        float p = fmaxf(u.x + v.x + t0 + bb0, 0.f) * wm0
                + fmaxf(u.y + v.y + t1 + bb1, 0.f) * wm1v;
        p += __shfl_xor(p, 32, 64);
        p += __shfl_xor(p, 16, 64);
        p += __shfl_xor(p, 8, 64);
        p += __shfl_xor(p, 4, 64);
        p += __shfl_xor(p, 2, 64);
        p += __shfl_xor(p, 1, 64);
        if (lane == 0) outp[e] = p + bm2v;
    }
}

extern "C" void kernel_launch(void* const* d_in, const int* in_sizes, int n_in,
                              void* d_out, int out_size, void* d_ws, size_t ws_size,
                              hipStream_t stream) {
    const float* x     = (const float*)d_in[0];
    const int*   mp    = (const int*)d_in[1];
    const int*   pe    = (const int*)d_in[2];
    const float* attr  = (const float*)d_in[3];
    const float* W1_l  = (const float*)d_in[4];
    const float* b1    = (const float*)d_in[5];
    const float* W1_r  = (const float*)d_in[6];
    const float* W2_l  = (const float*)d_in[7];
    const float* b2    = (const float*)d_in[8];
    const float* W2_r  = (const float*)d_in[9];
    const float* Wm1   = (const float*)d_in[10];
    const float* bm1   = (const float*)d_in[11];
    const float* Wm2   = (const float*)d_in[12];
    const float* bm2   = (const float*)d_in[13];
    float* out = (float*)d_out;

    const int n_nodes = in_sizes[0] / HIDDEN;   // 50000
    const int n_mp    = in_sizes[1] / 2;        // 800000
    const int n_pred  = in_sizes[2] / 2;        // 400000

    const int* mp_src = mp;
    const int* mp_dst = mp + n_mp;
    const int* p_src  = pe;
    const int* p_dst  = pe + n_pred;

    char* ws = (char*)d_ws;
    size_t off = 0;
    auto alloc = [&](size_t bytes) -> void* {
        void* p = ws + off;
        off += (bytes + 255) & ~(size_t)255;
        return p;
    };
    short* Wc1h = (short*)alloc(8 * 8 * 64 * 8 * sizeof(short));
    short* Wc1l = (short*)alloc(8 * 8 * 64 * 8 * sizeof(short));
    short* Wc2h = (short*)alloc(8 * 8 * 64 * 8 * sizeof(short));
    short* Wc2l = (short*)alloc(8 * 8 * 64 * 8 * sizeof(short));
    short* Buvh = (short*)alloc(4 * 16 * 64 * 8 * sizeof(short));
    short* Buvl = (short*)alloc(4 * 16 * 64 * 8 * sizeof(short));
    int*   deg    = (int*)alloc((size_t)n_nodes * sizeof(int));
    int*   rowst  = (int*)alloc(((size_t)n_nodes + 1) * sizeof(int));
    int*   cursor = (int*)alloc((size_t)n_nodes * sizeof(int));
    int*   part   = (int*)alloc(64 * sizeof(int));
    int*   csr    = (int*)alloc((size_t)n_mp * sizeof(int));
    short* Xh  = (short*)alloc((size_t)n_nodes * HIDDEN * sizeof(short));
    short* Xl  = (short*)alloc((size_t)n_nodes * HIDDEN * sizeof(short));
    short* Mh  = (short*)alloc((size_t)n_nodes * HIDDEN * sizeof(short));
    short* Ml  = (short*)alloc((size_t)n_nodes * HIDDEN * sizeof(short));
    short* H1h = (short*)alloc((size_t)n_nodes * HIDDEN * sizeof(short));
    short* H1l = (short*)alloc((size_t)n_nodes * HIDDEN * sizeof(short));
    short* H2h = (short*)alloc((size_t)n_nodes * HIDDEN * sizeof(short));
    short* H2l = (short*)alloc((size_t)n_nodes * HIDDEN * sizeof(short));
    float* Ubuf = (float*)alloc((size_t)n_nodes * HIDDEN * sizeof(float));
    float* Vbuf = (float*)alloc((size_t)n_nodes * HIDDEN * sizeof(float));
    (void)ws_size; (void)n_in; (void)out_size;

    const int P = (n_nodes + 1023) / 1024;        // 49 scan blocks (<=64)
    const int degb = (n_nodes + 255) / 256;       // deg-zero blocks
    const int nsplit4 = n_nodes * 32;             // float4 groups in x
    const int splitb = (nsplit4 + 255) / 256;

    // fused prep: packs + deg zero + x split
    k_prep<<<48 + degb + splitb, 256, 0, stream>>>(x, W1_l, W1_r, W2_l, W2_r, Wm1,
                                                   Wc1h, Wc1l, Wc2h, Wc2l, Buvh, Buvl,
                                                   Xh, Xl, deg, n_nodes, degb, nsplit4);

    // CSR build
    k_deg<<<(n_mp + 255) / 256, 256, 0, stream>>>(mp_dst, deg, n_mp);
    k_scan_blk<<<P, 1024, 0, stream>>>(deg, rowst, part, n_nodes);
    k_scan_top<<<1, 64, 0, stream>>>(part, rowst, P, n_nodes);
    k_scan_add<<<P, 1024, 0, stream>>>(rowst, cursor, part, n_nodes);
    k_fill<<<(n_mp + 255) / 256, 256, 0, stream>>>(mp_src, mp_dst, cursor, csr, n_mp);

    // conv1
    k_agg_f32<<<(n_nodes + 3) / 4, 256, 0, stream>>>(x, rowst, csr, Mh, Ml, n_nodes);
    k_convm<<<(n_nodes + 31) / 32, 256, 0, stream>>>(Mh, Ml, Xh, Xl, Wc1h, Wc1l, b1,
                                                     H1h, H1l, n_nodes);
    // conv2
    k_agg_sp<<<(n_nodes + 3) / 4, 256, 0, stream>>>(H1h, H1l, rowst, csr, Mh, Ml, n_nodes);
    k_convm<<<(n_nodes + 31) / 32, 256, 0, stream>>>(Mh, Ml, H1h, H1l, Wc2h, Wc2l, b2,
                                                     H2h, H2l, n_nodes);

    // UV GEMM + streaming edge MLP
    k_guv<<<(n_nodes + 31) / 32, 256, 0, stream>>>(H2h, H2l, Buvh, Buvl, Ubuf, Vbuf, n_nodes);
    k_edge<<<2048, 256, 0, stream>>>(Ubuf, Vbuf, p_src, p_dst, attr, Wm1,
                                     bm1, Wm2, bm2, out, n_pred);
}